// Round 13
// baseline (167.140 us; speedup 1.0000x reference)
//
#include <hip/hip_runtime.h>
#include <stdint.h>

#define B_ 4
#define T_ 4096
#define D_ 512
#define H_ 8
#define HD_ 64
#define W_ 5
#define M_ (B_*T_)     // 16384 rows
#define TILE 128       // tokens per block
#define HALO 16        // >= dil*2 (layer==1 -> dil=2 needs 8); 16 rounds TMg to 160
#define TMg 160        // GEMM rows: TILE + 2*HALO
#define TN 192         // qh|kh|vh
#define LSTR 72        // attn LDS row stride (16B-aligned, breaks conflicts)

// GEMM staging: 2 ping-pong A-only k-step buffers (BK=32): A[160*32]
// (B/weights now loaded DIRECTLY global->reg; no LDS staging for B: r12
// audit put the LDS pipe at ~30us, the largest term; B removal cuts GEMM
// LDS reads 8->5/wave-step and staging writes 45->20KB/step.)
#define STEP_ 5120     // shorts per A step buffer (10240 B)
// attn overlay: Qs[128*72] Ks[160*72] Vs[160*72] = 32256 shorts > 2*STEP_
#define SH_ELEMS 32256 // 64512 B union

// k-chunk rotation inside each 64B staging row: phys = (qd + (row>>1)) & 3.
// Verified r7: SQ_LDS_BANK_CONFLICT 5.57M -> 1.38M.
#define KROT(row, qd) (((((qd) + ((row) >> 1)) & 3)) << 3)

typedef __attribute__((ext_vector_type(8))) short short8;
typedef __attribute__((ext_vector_type(4))) float floatx4;
typedef _Float16 h2 __attribute__((ext_vector_type(2)));

__device__ __forceinline__ unsigned short f2bf(float f) {
    unsigned int u = __builtin_bit_cast(unsigned int, f);
    u += 0x7fffu + ((u >> 16) & 1u);          // RNE
    return (unsigned short)(u >> 16);
}

// async global->LDS, 16B/lane; LDS dest = wave-uniform base + lane*16
__device__ __forceinline__ void async16(const unsigned short* g, unsigned short* l) {
    __builtin_amdgcn_global_load_lds(
        (const __attribute__((address_space(1))) unsigned int*)g,
        (__attribute__((address_space(3))) unsigned int*)l, 16, 0, 0);
}

// ------------- prep: convert X (fp32->bf16) + build Wt2 ------------------
__global__ __launch_bounds__(256) void prep(const float* __restrict__ x,
                                            const float* __restrict__ Wq,
                                            const float* __restrict__ Wk,
                                            const float* __restrict__ Wv,
                                            unsigned short* __restrict__ xb,
                                            unsigned short* __restrict__ Wt2) {
    int bx = blockIdx.x;
    if (bx < 4096) {
        int i = bx * 256 + threadIdx.x;
        const float4* x4 = (const float4*)x;
        float4 a = x4[2*i], b = x4[2*i + 1];
        uint4 o;
        o.x = (unsigned)f2bf(a.x) | ((unsigned)f2bf(a.y) << 16);
        o.y = (unsigned)f2bf(a.z) | ((unsigned)f2bf(a.w) << 16);
        o.z = (unsigned)f2bf(b.x) | ((unsigned)f2bf(b.y) << 16);
        o.w = (unsigned)f2bf(b.z) | ((unsigned)f2bf(b.w) << 16);
        ((uint4*)xb)[i] = o;
    } else {
        int tid = (bx - 4096) * 256 + threadIdx.x;   // 1536*64 threads
        int np = tid % 1536;                         // h*192 + n192
        int kc = tid / 1536;                         // k chunk of 8
        int h = np / 192, n192 = np % 192;
        int sel = n192 >> 6, ch = n192 & 63;
        int c = h * 64 + ch;
        const float* Wsrc = (sel == 0) ? Wq : ((sel == 1) ? Wk : Wv);
        unsigned short us[8];
#pragma unroll
        for (int j = 0; j < 8; j++)
            us[j] = f2bf(Wsrc[(size_t)(kc*8 + j) * D_ + c]);
        uint4 o;
        o.x = (unsigned)us[0] | ((unsigned)us[1] << 16);
        o.y = (unsigned)us[2] | ((unsigned)us[3] << 16);
        o.z = (unsigned)us[4] | ((unsigned)us[5] << 16);
        o.w = (unsigned)us[6] | ((unsigned)us[7] << 16);
        *(uint4*)(Wt2 + (size_t)np * D_ + kc*8) = o;
    }
}

// -------- fused per-head QKV GEMM + windowed attention, 512-thread --------
// grid 1024; T1 remap: tile = bx&127, h = bx>>7 -> XCD id = tile%8, all 8
// head-blocks of a tile share one XCD L2 (r8: FETCH 67->26MB; also makes
// Wt2 L2-resident, enabling direct global->reg B loads below).
// Phase 1: 160x192x512 bf16 GEMM as 16 BK=32 k-steps.  A: double-buffered
//   LDS (KROT-swizzled, conflict-free).  B: direct global->reg b128 loads
//   (L2-hot, no block-level reuse to exploit) issued post-MFMA for step
//   s+1 so the step-end __syncthreads drain completes them.  8 waves,
//   wave-tile 80x48.
// Phase 2: +bias -> LDS q/k/v as F16.  Phase 3: windowed softmax + PV in
//   packed f16 (v_dot2_f32_f16 / v_pk_fma_f16; r12: VALU 34.5->28.8%).
// LDS 65536 B -> 2 blocks/CU = 16 waves/CU.
__global__ __launch_bounds__(512, 4) void fused_qkv_attn(
    const unsigned short* __restrict__ Xb,   // [M_,512] bf16
    const unsigned short* __restrict__ Wt2,  // [8,192,512] bf16
    const float* __restrict__ bq, const float* __restrict__ bk2,
    const float* __restrict__ bv, const float* __restrict__ Er,
    const int* __restrict__ layer_p,
    float* __restrict__ out,                 // [B_,T_,512] fp32
    float* __restrict__ attn_out)            // [B_,8,T_,5] fp32
{
    __shared__ unsigned short SH[SH_ELEMS];        // 64512 B union
    __shared__ unsigned int sErP[W_ * 32];         // 640 B: f16-pair Er[w][pair]
    unsigned short* Qs = SH;                       // attn phase overlay (f16)
    unsigned short* Ks = SH + TILE * LSTR;
    unsigned short* Vs = SH + (TILE + TMg) * LSTR;

    const int tid = threadIdx.x;
    const int wave = tid >> 6, lane = tid & 63;
    const int tile = blockIdx.x & 127, h = blockIdx.x >> 7;   // T1 remap
    const int b = tile >> 5;                 // 32 tiles per batch
    const int t0 = (tile & 31) * TILE;
    const long m0g = (long)b * T_ + t0;

    // Er pair -> registers now (pair p covers d=2p,2p+1 of window ew), LDS in
    // epilogue as packed f16.
    float eLo = 0.f, eHi = 0.f;
    const int ep = tid & 31, ew = tid >> 5;
    if (tid < 160) {
        eLo = Er[h * HD_ * W_ + (2*ep)     * W_ + ew];
        eHi = Er[h * HD_ * W_ + (2*ep + 1) * W_ + ew];
    }

    // A staging: 10 rows per k-step, each 16 tile-rows x 64B = one async16.
    // wave w takes q = w + 8j (j<2); waves 0,1 have 2 rows, others 1.
    // Pre-swizzled source (KROT inverse on the global k-chunk).
    const int gchunk = ((lane & 3) - ((lane >> 3) & 3)) & 3;
    const unsigned short* gsrc[2] = {Xb, Xb};
    int ldoff[2] = {0, 0};
#pragma unroll
    for (int j = 0; j < 2; j++) {
        int q = wave + j * 8;
        if (q < 10) {
            long grow = m0g - HALO + q*16 + (lane >> 2);
            grow = grow < 0 ? 0 : (grow >= M_ ? M_ - 1 : grow);  // halo clamp; masked later
            gsrc[j] = Xb + grow * D_ + gchunk * 8;
            ldoff[j] = q * 512;
        }
    }

    auto issueA = [&](int ss) {                    // stage A k-step ss
        unsigned short* bb = SH + (ss & 1) * STEP_;
#pragma unroll
        for (int j = 0; j < 2; j++)
            if (wave + j * 8 < 10)
                async16(gsrc[j] + ss * 32, bb + ldoff[j]);
    };

    const int wm = (wave >> 2) * 80;         // 2 row-groups x 4 col-groups
    const int wn = (wave & 3) * 48;          // wave-tile 80 x 48
    const int qd = lane >> 4, r16 = lane & 15;
    floatx4 acc[5][3] = {};

    // per-lane B-fragment base pointers (L2-resident weights)
    const unsigned short* bptr[3];
#pragma unroll
    for (int ni = 0; ni < 3; ni++)
        bptr[ni] = Wt2 + ((size_t)h*TN + wn + ni*16 + r16) * D_ + qd*8;

    short8 bfr[3];
#pragma unroll
    for (int ni = 0; ni < 3; ni++)          // B(0) -> regs
        bfr[ni] = __builtin_bit_cast(short8, *(const uint4*)(bptr[ni]));

    issueA(0);
    __syncthreads();                         // step 0 A resident, B(0) drained

    #pragma unroll
    for (int s = 0; s < 16; s++) {
        if (s < 15) issueA(s + 1);           // prefetch next A step (other buffer)

        const unsigned short* bufA = SH + (s & 1) * STEP_;
        short8 af[5];
#pragma unroll
        for (int mi = 0; mi < 5; mi++) {
            int row = wm + mi*16 + r16;
            af[mi] = __builtin_bit_cast(short8,
                *(const uint4*)(bufA + row*32 + KROT(row, qd)));
        }

        __builtin_amdgcn_s_setprio(1);
#pragma unroll
        for (int mi = 0; mi < 5; mi++)
#pragma unroll
            for (int ni = 0; ni < 3; ni++)
                acc[mi][ni] = __builtin_amdgcn_mfma_f32_16x16x32_bf16(
                    af[mi], bfr[ni], acc[mi][ni], 0, 0, 0);
        __builtin_amdgcn_s_setprio(0);

        if (s < 15) {                        // B(s+1) -> regs (WAR after MFMA);
#pragma unroll                               // step-end drain completes them
            for (int ni = 0; ni < 3; ni++)
                bfr[ni] = __builtin_bit_cast(short8,
                    *(const uint4*)(bptr[ni] + (s + 1) * 32));
        }

        __syncthreads();                     // drain AFTER compute; 1 barrier/step
    }

    // ---- epilogue: +bias, f16-convert, scatter to Q/K/V LDS tiles --------
#pragma unroll
    for (int ni = 0; ni < 3; ni++) {
        int n192 = wn + ni * 16 + r16;
        int sel = n192 >> 6;                 // uniform per (wave, ni)
        int ch = n192 & 63;
        float bias = (sel == 0) ? bq[h*64 + ch]
                   : (sel == 1) ? bk2[h*64 + ch] : bv[h*64 + ch];
#pragma unroll
        for (int mi = 0; mi < 5; mi++)
#pragma unroll
            for (int r = 0; r < 4; r++) {
                int l = wm + mi*16 + qd*4 + r;    // 0..159
                unsigned short vb = __builtin_bit_cast(unsigned short,
                                        (_Float16)(acc[mi][ni][r] + bias));
                if (sel == 0) {
                    if (l >= HALO && l < HALO + TILE)
                        Qs[(l - HALO) * LSTR + ch] = vb;
                } else if (sel == 1) {
                    Ks[l * LSTR + ch] = vb;
                } else {
                    Vs[l * LSTR + ch] = vb;
                }
            }
    }
    if (tid < 160) {
        h2 ep2 = { (_Float16)eLo, (_Float16)eHi };
        sErP[ew * 32 + ep] = __builtin_bit_cast(unsigned int, ep2);
    }
    __syncthreads();

    // ---- attention from LDS (f16 packed): 8 lanes/token, 2 passes --------
    const int dil = 1 << layer_p[0];
    const int sh = (h < 4) ? 0 : (h == 4 ? -2 : (h == 5 ? -1 : (h == 6 ? 1 : 2)));
    const int c8 = tid & 7, g64 = tid >> 3;  // 64 token-groups

#pragma unroll
    for (int p = 0; p < 2; p++) {
        int tl = g64 + p * 64;               // local token 0..127
        int t = t0 + tl;
        uint4 qv = *(const uint4*)(Qs + tl * LSTR + c8 * 8);
        h2 qp[4] = { __builtin_bit_cast(h2, qv.x), __builtin_bit_cast(h2, qv.y),
                     __builtin_bit_cast(h2, qv.z), __builtin_bit_cast(h2, qv.w) };

        int pos[W_]; bool val[W_]; float s[W_];
#pragma unroll
        for (int w = 0; w < W_; w++) {
            pos[w] = t + (sh + w - 2) * dil;
            val[w] = (pos[w] >= 0) && (pos[w] < T_);
            float a = 0.f;
            if (val[w]) {
                uint4 kv = *(const uint4*)(Ks + (pos[w] - t0 + HALO) * LSTR + c8 * 8);
                a = __builtin_amdgcn_fdot2(qp[0], __builtin_bit_cast(h2, kv.x), a, false);
                a = __builtin_amdgcn_fdot2(qp[1], __builtin_bit_cast(h2, kv.y), a, false);
                a = __builtin_amdgcn_fdot2(qp[2], __builtin_bit_cast(h2, kv.z), a, false);
                a = __builtin_amdgcn_fdot2(qp[3], __builtin_bit_cast(h2, kv.w), a, false);
            }
#pragma unroll
            for (int i = 0; i < 4; i++)
                a = __builtin_amdgcn_fdot2(qp[i],
                        __builtin_bit_cast(h2, sErP[w * 32 + c8 * 4 + i]), a, false);
            s[w] = a;
        }
#pragma unroll
        for (int off = 4; off > 0; off >>= 1)
#pragma unroll
            for (int w = 0; w < W_; w++)
                s[w] += __shfl_xor(s[w], off, 8);

        float logit[W_], mx = -1e30f;
#pragma unroll
        for (int w = 0; w < W_; w++) {
            logit[w] = val[w] ? s[w] * 0.125f : -1e30f;
            mx = fmaxf(mx, logit[w]);
        }
        float pw[W_], ssum = 0.f;
#pragma unroll
        for (int w = 0; w < W_; w++) {
            pw[w] = val[w] ? __expf(logit[w] - mx) : 0.f;
            ssum += pw[w];
        }
        const float inv = 1.f / ssum;
        float aw[W_];
#pragma unroll
        for (int w = 0; w < W_; w++) aw[w] = pw[w] * inv;

        if (c8 < W_)
            attn_out[((size_t)(b * H_ + h) * T_ + t) * W_ + c8] = aw[c8];

        h2 of2[4] = {h2{0,0}, h2{0,0}, h2{0,0}, h2{0,0}};
#pragma unroll
        for (int w = 0; w < W_; w++) {
            if (val[w]) {
                uint4 vv = *(const uint4*)(Vs + (pos[w] - t0 + HALO) * LSTR + c8 * 8);
                _Float16 awh = (_Float16)aw[w];
                h2 aw2 = { awh, awh };
                of2[0] = __builtin_bit_cast(h2, vv.x) * aw2 + of2[0];
                of2[1] = __builtin_bit_cast(h2, vv.y) * aw2 + of2[1];
                of2[2] = __builtin_bit_cast(h2, vv.z) * aw2 + of2[2];
                of2[3] = __builtin_bit_cast(h2, vv.w) * aw2 + of2[3];
            }
        }
        float* orow = out + ((size_t)b * T_ + t) * D_ + h * HD_ + c8 * 8;
        *(float4*)(orow)     = make_float4((float)of2[0][0], (float)of2[0][1],
                                           (float)of2[1][0], (float)of2[1][1]);
        *(float4*)(orow + 4) = make_float4((float)of2[2][0], (float)of2[2][1],
                                           (float)of2[3][0], (float)of2[3][1]);
    }
}

extern "C" void kernel_launch(void* const* d_in, const int* in_sizes, int n_in,
                              void* d_out, int out_size, void* d_ws, size_t ws_size,
                              hipStream_t stream) {
    const float* x   = (const float*)d_in[0];
    const float* Wq  = (const float*)d_in[1];
    const float* bq  = (const float*)d_in[2];
    const float* Wk  = (const float*)d_in[3];
    const float* bk  = (const float*)d_in[4];
    const float* Wv  = (const float*)d_in[5];
    const float* bv  = (const float*)d_in[6];
    const float* Er  = (const float*)d_in[7];
    const int* layer = (const int*)d_in[8];

    char* ws = (char*)d_ws;
    unsigned short* Xb  = (unsigned short*)ws;                          // 16 MB
    unsigned short* Wt2 = (unsigned short*)(ws + (size_t)16*1024*1024); // 1.5 MB

    float* out  = (float*)d_out;
    float* attn = out + (size_t)B_ * T_ * D_;

    prep<<<4096 + 384, 256, 0, stream>>>(x, Wq, Wk, Wv, Xb, Wt2);
    fused_qkv_attn<<<(M_ / TILE) * 8, 512, 0, stream>>>(Xb, Wt2, bq, bk, bv,
                                                        Er, layer, out, attn);
}

// Round 15
// 145.011 us; speedup vs baseline: 1.1526x; 1.1526x over previous
//
#include <hip/hip_runtime.h>
#include <stdint.h>

#define B_ 4
#define T_ 4096
#define D_ 512
#define H_ 8
#define HD_ 64
#define W_ 5
#define M_ (B_*T_)     // 16384 rows
#define TILE 128       // tokens per block
#define HALO 8         // layer==1 -> dil=2 -> max reach 4*dil = 8 (r4/r5 proven)
#define TMg 144        // GEMM rows: TILE + 2*HALO
#define TN 192         // qh|kh|vh

// GEMM staging: 2 ping-pong k-step buffers (BK=32), each A[144*32]+B[192*32]
#define STEP_ 10752    // shorts per step buffer (21504 B)
#define BOFF_ 4608     // B region offset inside a step buffer (shorts)
// attn overlay: Qs[128*64] Ks[144*64] Vs[144*64] = 26624 shorts (53248 B),
// XOR slot-swizzle keeps reads conflict-free at stride 64 (r4 layout).
#define SH_ELEMS 26624 // 53248 B union (staging 43008 B fits inside)
// + sErP 640 B -> alloc 54272 B -> 3 blocks/CU = 24 waves/CU (+50% TLP vs r12).
// launch_bounds stays (512,4): reg cap 128, VGPR ~64 -> no spill (r4 lesson).

// k-chunk rotation inside each 64B staging row: phys = (qd + (row>>1)) & 3.
// Verified r7: SQ_LDS_BANK_CONFLICT 5.57M -> 1.38M.
#define KROT(row, qd) (((((qd) + ((row) >> 1)) & 3)) << 3)

typedef __attribute__((ext_vector_type(8))) short short8;
typedef __attribute__((ext_vector_type(4))) float floatx4;
typedef _Float16 h2 __attribute__((ext_vector_type(2)));

__device__ __forceinline__ unsigned short f2bf(float f) {
    unsigned int u = __builtin_bit_cast(unsigned int, f);
    u += 0x7fffu + ((u >> 16) & 1u);          // RNE
    return (unsigned short)(u >> 16);
}

// attn overlay addressing: element (row, ch) -> physical short index
__device__ __forceinline__ int swz(int row, int ch) {
    return row * 64 + ((((ch >> 3) ^ (row & 7)) << 3) | (ch & 7));
}
// 16B-aligned base for an 8-short slot read
__device__ __forceinline__ int swz8(int row, int c8) {
    return row * 64 + ((c8 ^ (row & 7)) << 3);
}

// async global->LDS, 16B/lane; LDS dest = wave-uniform base + lane*16
__device__ __forceinline__ void async16(const unsigned short* g, unsigned short* l) {
    __builtin_amdgcn_global_load_lds(
        (const __attribute__((address_space(1))) unsigned int*)g,
        (__attribute__((address_space(3))) unsigned int*)l, 16, 0, 0);
}

// ------------- prep: convert X (fp32->bf16) + build Wt2 ------------------
__global__ __launch_bounds__(256) void prep(const float* __restrict__ x,
                                            const float* __restrict__ Wq,
                                            const float* __restrict__ Wk,
                                            const float* __restrict__ Wv,
                                            unsigned short* __restrict__ xb,
                                            unsigned short* __restrict__ Wt2) {
    int bx = blockIdx.x;
    if (bx < 4096) {
        int i = bx * 256 + threadIdx.x;
        const float4* x4 = (const float4*)x;
        float4 a = x4[2*i], b = x4[2*i + 1];
        uint4 o;
        o.x = (unsigned)f2bf(a.x) | ((unsigned)f2bf(a.y) << 16);
        o.y = (unsigned)f2bf(a.z) | ((unsigned)f2bf(a.w) << 16);
        o.z = (unsigned)f2bf(b.x) | ((unsigned)f2bf(b.y) << 16);
        o.w = (unsigned)f2bf(b.z) | ((unsigned)f2bf(b.w) << 16);
        ((uint4*)xb)[i] = o;
    } else {
        int tid = (bx - 4096) * 256 + threadIdx.x;   // 1536*64 threads
        int np = tid % 1536;                         // h*192 + n192
        int kc = tid / 1536;                         // k chunk of 8
        int h = np / 192, n192 = np % 192;
        int sel = n192 >> 6, ch = n192 & 63;
        int c = h * 64 + ch;
        const float* Wsrc = (sel == 0) ? Wq : ((sel == 1) ? Wk : Wv);
        unsigned short us[8];
#pragma unroll
        for (int j = 0; j < 8; j++)
            us[j] = f2bf(Wsrc[(size_t)(kc*8 + j) * D_ + c]);
        uint4 o;
        o.x = (unsigned)us[0] | ((unsigned)us[1] << 16);
        o.y = (unsigned)us[2] | ((unsigned)us[3] << 16);
        o.z = (unsigned)us[4] | ((unsigned)us[5] << 16);
        o.w = (unsigned)us[6] | ((unsigned)us[7] << 16);
        *(uint4*)(Wt2 + (size_t)np * D_ + kc*8) = o;
    }
}

// -------- fused per-head QKV GEMM + windowed attention, 512-thread --------
// grid 1024; T1 remap: tile = bx&127, h = bx>>7 -> XCD id = tile%8, all 8
// head-blocks of a tile share one XCD L2 (r8: FETCH 67->26MB).
// Phase 1: 144x192x512 bf16 GEMM as 16 BK=32 k-steps, double-buffered LDS,
//   issue-early 2-phase schedule (r12 structure, proven 56.5us).  KROT-
//   swizzled staging.  Asymmetric wave-tiles: rg0 rows 0-79 (5 frags),
//   rg1 rows 80-143 (4 frags); wave-uniform guards, reg cap 128 (no spill).
// Phase 2: +bias -> swizzled stride-64 LDS q/k/v as F16.
// Phase 3: windowed softmax + PV in packed f16 (fdot2 / pk_fma).
// LDS 54272 B -> 3 blocks/CU = 24 waves/CU.
__global__ __launch_bounds__(512, 4) void fused_qkv_attn(
    const unsigned short* __restrict__ Xb,   // [M_,512] bf16
    const unsigned short* __restrict__ Wt2,  // [8,192,512] bf16
    const float* __restrict__ bq, const float* __restrict__ bk2,
    const float* __restrict__ bv, const float* __restrict__ Er,
    const int* __restrict__ layer_p,
    float* __restrict__ out,                 // [B_,T_,512] fp32
    float* __restrict__ attn_out)            // [B_,8,T_,5] fp32
{
    __shared__ unsigned short SH[SH_ELEMS];        // 53248 B union
    __shared__ unsigned int sErP[W_ * 32];         // 640 B: f16-pair Er[w][pair]
    unsigned short* Qs = SH;                       // attn phase overlay (f16)
    unsigned short* Ks = SH + TILE * 64;
    unsigned short* Vs = SH + (TILE + TMg) * 64;

    const int tid = threadIdx.x;
    const int wave = tid >> 6, lane = tid & 63;
    const int tile = blockIdx.x & 127, h = blockIdx.x >> 7;   // T1 remap
    const int b = tile >> 5;                 // 32 tiles per batch
    const int t0 = (tile & 31) * TILE;
    const long m0g = (long)b * T_ + t0;

    // Er pair -> registers now, LDS (packed f16) in epilogue
    float eLo = 0.f, eHi = 0.f;
    const int ep = tid & 31, ew = tid >> 5;
    if (tid < 160) {
        eLo = Er[h * HD_ * W_ + (2*ep)     * W_ + ew];
        eHi = Er[h * HD_ * W_ + (2*ep + 1) * W_ + ew];
    }

    // 21 staging rows per k-step (A:9, B:12), each 16 tile-rows x 64B = one
    // async16. wave w takes q = w + 8j (j<3); waves 5-7 have only 2.
    // Pre-swizzled source (KROT inverse on the global k-chunk).
    const int gchunk = ((lane & 3) - ((lane >> 3) & 3)) & 3;
    const unsigned short* gsrc[3] = {Xb, Xb, Xb};
    int ldoff[3] = {0, 0, 0};
#pragma unroll
    for (int j = 0; j < 3; j++) {
        int q = wave + j * 8;
        if (q < 21) {
            if (q < 9) {
                long grow = m0g - HALO + q*16 + (lane >> 2);
                grow = grow < 0 ? 0 : (grow >= M_ ? M_ - 1 : grow);  // halo clamp
                gsrc[j] = Xb + grow * D_ + gchunk * 8;
                ldoff[j] = q * 512;
            } else {
                int q2 = q - 9;
                gsrc[j] = Wt2 + ((size_t)h*TN + q2*16 + (lane >> 2)) * D_ + gchunk * 8;
                ldoff[j] = BOFF_ + q2 * 512;
            }
        }
    }

    auto issue = [&](int ss) {                     // stage k-step ss
        unsigned short* bb = SH + (ss & 1) * STEP_;
#pragma unroll
        for (int j = 0; j < 3; j++)
            if (wave + j * 8 < 21)
                async16(gsrc[j] + ss * 32, bb + ldoff[j]);
    };

    const int rg = wave >> 2;                // rg0: rows 0-79; rg1: rows 80-143
    const int wm = rg * 80;
    const int nm = rg ? 4 : 5;               // frag-rows per wave (uniform)
    const int wn = (wave & 3) * 48;          // 4 col-groups of 48
    const int qd = lane >> 4, r16 = lane & 15;
    floatx4 acc[5][3] = {};

    issue(0);
    __syncthreads();                         // step 0 resident

    #pragma unroll
    for (int s = 0; s < 16; s++) {
        if (s < 15) issue(s + 1);            // prefetch next step (other buffer)

        const unsigned short* bufA = SH + (s & 1) * STEP_;
        const unsigned short* bufB = bufA + BOFF_;
        short8 af[5], bfr[3];
#pragma unroll
        for (int mi = 0; mi < 5; mi++)
            if (mi < nm) {
                int row = wm + mi*16 + r16;
                af[mi] = __builtin_bit_cast(short8,
                    *(const uint4*)(bufA + row*32 + KROT(row, qd)));
            }
#pragma unroll
        for (int ni = 0; ni < 3; ni++) {
            int row = wn + ni*16 + r16;
            bfr[ni] = __builtin_bit_cast(short8,
                *(const uint4*)(bufB + row*32 + KROT(row, qd)));
        }

        __builtin_amdgcn_s_setprio(1);
#pragma unroll
        for (int mi = 0; mi < 5; mi++)
            if (mi < nm)
#pragma unroll
                for (int ni = 0; ni < 3; ni++)
                    acc[mi][ni] = __builtin_amdgcn_mfma_f32_16x16x32_bf16(
                        af[mi], bfr[ni], acc[mi][ni], 0, 0, 0);
        __builtin_amdgcn_s_setprio(0);

        __syncthreads();                     // drain AFTER compute; 1 barrier/step
    }

    // ---- epilogue: +bias, f16-convert, scatter to swizzled Q/K/V tiles ---
#pragma unroll
    for (int ni = 0; ni < 3; ni++) {
        int n192 = wn + ni * 16 + r16;
        int sel = n192 >> 6;                 // uniform per (wave, ni)
        int ch = n192 & 63;
        float bias = (sel == 0) ? bq[h*64 + ch]
                   : (sel == 1) ? bk2[h*64 + ch] : bv[h*64 + ch];
#pragma unroll
        for (int mi = 0; mi < 5; mi++)
            if (mi < nm)
#pragma unroll
                for (int r = 0; r < 4; r++) {
                    int l = wm + mi*16 + qd*4 + r;    // 0..143
                    unsigned short vb = __builtin_bit_cast(unsigned short,
                                            (_Float16)(acc[mi][ni][r] + bias));
                    if (sel == 0) {
                        if (l >= HALO && l < HALO + TILE)
                            Qs[swz(l - HALO, ch)] = vb;
                    } else if (sel == 1) {
                        Ks[swz(l, ch)] = vb;
                    } else {
                        Vs[swz(l, ch)] = vb;
                    }
                }
    }
    if (tid < 160) {
        h2 ep2 = { (_Float16)eLo, (_Float16)eHi };
        sErP[ew * 32 + ep] = __builtin_bit_cast(unsigned int, ep2);
    }
    __syncthreads();

    // ---- attention from LDS (f16 packed): 8 lanes/token, 2 passes --------
    const int dil = 1 << layer_p[0];
    const int sh = (h < 4) ? 0 : (h == 4 ? -2 : (h == 5 ? -1 : (h == 6 ? 1 : 2)));
    const int c8 = tid & 7, g64 = tid >> 3;  // 64 token-groups

#pragma unroll
    for (int p = 0; p < 2; p++) {
        int tl = g64 + p * 64;               // local token 0..127
        int t = t0 + tl;
        uint4 qv = *(const uint4*)(Qs + swz8(tl, c8));
        h2 qp[4] = { __builtin_bit_cast(h2, qv.x), __builtin_bit_cast(h2, qv.y),
                     __builtin_bit_cast(h2, qv.z), __builtin_bit_cast(h2, qv.w) };

        int pos[W_]; bool val[W_]; float s[W_];
#pragma unroll
        for (int w = 0; w < W_; w++) {
            pos[w] = t + (sh + w - 2) * dil;
            val[w] = (pos[w] >= 0) && (pos[w] < T_);
            float a = 0.f;
            if (val[w]) {
                uint4 kv = *(const uint4*)(Ks + swz8(pos[w] - t0 + HALO, c8));
                a = __builtin_amdgcn_fdot2(qp[0], __builtin_bit_cast(h2, kv.x), a, false);
                a = __builtin_amdgcn_fdot2(qp[1], __builtin_bit_cast(h2, kv.y), a, false);
                a = __builtin_amdgcn_fdot2(qp[2], __builtin_bit_cast(h2, kv.z), a, false);
                a = __builtin_amdgcn_fdot2(qp[3], __builtin_bit_cast(h2, kv.w), a, false);
            }
#pragma unroll
            for (int i = 0; i < 4; i++)
                a = __builtin_amdgcn_fdot2(qp[i],
                        __builtin_bit_cast(h2, sErP[w * 32 + c8 * 4 + i]), a, false);
            s[w] = a;
        }
#pragma unroll
        for (int off = 4; off > 0; off >>= 1)
#pragma unroll
            for (int w = 0; w < W_; w++)
                s[w] += __shfl_xor(s[w], off, 8);

        float logit[W_], mx = -1e30f;
#pragma unroll
        for (int w = 0; w < W_; w++) {
            logit[w] = val[w] ? s[w] * 0.125f : -1e30f;
            mx = fmaxf(mx, logit[w]);
        }
        float pw[W_], ssum = 0.f;
#pragma unroll
        for (int w = 0; w < W_; w++) {
            pw[w] = val[w] ? __expf(logit[w] - mx) : 0.f;
            ssum += pw[w];
        }
        const float inv = 1.f / ssum;
        float aw[W_];
#pragma unroll
        for (int w = 0; w < W_; w++) aw[w] = pw[w] * inv;

        if (c8 < W_)
            attn_out[((size_t)(b * H_ + h) * T_ + t) * W_ + c8] = aw[c8];

        h2 of2[4] = {h2{0,0}, h2{0,0}, h2{0,0}, h2{0,0}};
#pragma unroll
        for (int w = 0; w < W_; w++) {
            if (val[w]) {
                uint4 vv = *(const uint4*)(Vs + swz8(pos[w] - t0 + HALO, c8));
                _Float16 awh = (_Float16)aw[w];
                h2 aw2 = { awh, awh };
                of2[0] = __builtin_bit_cast(h2, vv.x) * aw2 + of2[0];
                of2[1] = __builtin_bit_cast(h2, vv.y) * aw2 + of2[1];
                of2[2] = __builtin_bit_cast(h2, vv.z) * aw2 + of2[2];
                of2[3] = __builtin_bit_cast(h2, vv.w) * aw2 + of2[3];
            }
        }
        float* orow = out + ((size_t)b * T_ + t) * D_ + h * HD_ + c8 * 8;
        *(float4*)(orow)     = make_float4((float)of2[0][0], (float)of2[0][1],
                                           (float)of2[1][0], (float)of2[1][1]);
        *(float4*)(orow + 4) = make_float4((float)of2[2][0], (float)of2[2][1],
                                           (float)of2[3][0], (float)of2[3][1]);
    }
}

extern "C" void kernel_launch(void* const* d_in, const int* in_sizes, int n_in,
                              void* d_out, int out_size, void* d_ws, size_t ws_size,
                              hipStream_t stream) {
    const float* x   = (const float*)d_in[0];
    const float* Wq  = (const float*)d_in[1];
    const float* bq  = (const float*)d_in[2];
    const float* Wk  = (const float*)d_in[3];
    const float* bk  = (const float*)d_in[4];
    const float* Wv  = (const float*)d_in[5];
    const float* bv  = (const float*)d_in[6];
    const float* Er  = (const float*)d_in[7];
    const int* layer = (const int*)d_in[8];

    char* ws = (char*)d_ws;
    unsigned short* Xb  = (unsigned short*)ws;                          // 16 MB
    unsigned short* Wt2 = (unsigned short*)(ws + (size_t)16*1024*1024); // 1.5 MB

    float* out  = (float*)d_out;
    float* attn = out + (size_t)B_ * T_ * D_;

    prep<<<4096 + 384, 256, 0, stream>>>(x, Wq, Wk, Wv, Xb, Wt2);
    fused_qkv_attn<<<(M_ / TILE) * 8, 512, 0, stream>>>(Xb, Wt2, bq, bk, bv,
                                                        Er, layer, out, attn);
}